// Round 7
// baseline (115.590 us; speedup 1.0000x reference)
//
#include <hip/hip_runtime.h>

#define BB 4
#define NN 4096

typedef __attribute__((ext_vector_type(8))) short short8v;   // 8 bf16 = 4 VGPRs
typedef __attribute__((ext_vector_type(4))) short short4v;   // 4 bf16 = 2 VGPRs
typedef __attribute__((ext_vector_type(4))) float float4v;   // MFMA acc

__device__ __forceinline__ unsigned short f2bf_rn(float f) {
    unsigned u = __float_as_uint(f);
    u += 0x7FFFu + ((u >> 16) & 1u);          // round-to-nearest-even
    return (unsigned short)(u >> 16);
}

// ---------------------------------------------------------------------------
// Kernel 1: fused QKV projection, scalar-broadcast GEMM, n-tile 32.
// Grid (128, 4) = 512 blocks (2/CU, 8 waves/CU). Thread -> (2 n, 5 o):
// per c-iter 1 float2 + 5 broadcast LDS reads feed 10 FMAs.
// Outputs: Qt[b][n][8], Kt[b][n][8] (16 B rows); Vsw 1 KB chunks per
// (b,ct,nb): elem[lane*8+j] = V[ct*16+(lane&15)][nb*32+(lane>>4)*8+j].
// ---------------------------------------------------------------------------
__global__ __launch_bounds__(256) void qkv_kernel(
    const float* __restrict__ x,
    const float* __restrict__ Wq, const float* __restrict__ Wk,
    const float* __restrict__ Wv,
    unsigned short* __restrict__ Qt, unsigned short* __restrict__ Kt,
    unsigned short* __restrict__ Vsw)
{
    __shared__ float xs[64][36];            // [c][n] fp32, pad 36 (144 B rows)
    __shared__ float wl[64][81];            // [c][o] transposed weights
    __shared__ unsigned short Ot[80][40];   // [o][n] bf16 staging (80 B rows)

    const int t  = threadIdx.x;
    const int b  = blockIdx.y;
    const int nb = blockIdx.x;               // 32-n tile == one Vsw chunk index
    const int n0 = nb * 32;

    // ---- stage weights transposed: wl[c][o] = W(o,c)
    #pragma unroll
    for (int i = 0; i < 20; ++i) {
        int idx = t + 256 * i;               // 5120 = 80*64
        int r = idx >> 6, c = idx & 63;
        float w;
        if (r < 8)       w = Wq[r * 64 + c];
        else if (r < 16) w = Wk[(r - 8) * 64 + c];
        else             w = Wv[(r - 16) * 64 + c];
        wl[c][r] = w;
    }
    // ---- stage x tile (64 c x 32 n) fp32, float4
    #pragma unroll
    for (int i = 0; i < 2; ++i) {
        int idx = t + 256 * i;               // 512 float4 slots
        int c = idx >> 3, n4 = (idx & 7) * 4;
        *(float4*)&xs[c][n4] = *(const float4*)&x[(size_t)(b * 64 + c) * NN + n0 + n4];
    }
    __syncthreads();

    const int n2 = (t & 15) * 2;             // this thread's 2 n's
    const int og = t >> 4;                   // 0..15 -> o rows og*5..og*5+4

    float acc[5][2];
    #pragma unroll
    for (int k = 0; k < 5; ++k) { acc[k][0] = 0.f; acc[k][1] = 0.f; }

    for (int c = 0; c < 64; ++c) {
        float2 xv = *(const float2*)&xs[c][n2];
        #pragma unroll
        for (int k = 0; k < 5; ++k) {
            float wv = wl[c][og * 5 + k];
            acc[k][0] += wv * xv.x;
            acc[k][1] += wv * xv.y;
        }
    }

    #pragma unroll
    for (int k = 0; k < 5; ++k) {
        Ot[og * 5 + k][n2]     = f2bf_rn(acc[k][0]);
        Ot[og * 5 + k][n2 + 1] = f2bf_rn(acc[k][1]);
    }
    __syncthreads();

    // ---- Qt/Kt writer: 16 B per n, coalesced
    if (t < 64) {
        int n = t & 31;
        int rbase = (t < 32) ? 0 : 8;
        short8v p;
        #pragma unroll
        for (int j = 0; j < 8; ++j) p[j] = (short)Ot[rbase + j][n];
        unsigned short* dst = ((t < 32) ? Qt : Kt) + ((size_t)b * NN + n0 + n) * 8;
        *(short8v*)dst = p;
    }

    // ---- swizzled Vsw writer: 4 ct-chunks of 1 KB, one 16 B piece/thread
    {
        int ct = t >> 6, l = t & 63;
        unsigned short* cb = Vsw + ((size_t)(b * 4 + ct) * 128 + nb) * 512;
        short8v d = *(short8v*)&Ot[16 + ct * 16 + (l & 15)][(l >> 4) * 8];
        *(short8v*)(cb + l * 8) = d;
    }
}

// ---------------------------------------------------------------------------
// Kernel 2: MFMA streaming attention, 64-wide m-tile, LDS-shared V.
// Grid (64, 4) = 256 blocks (1/CU). Block = 4 waves w: mh = w&1 (m-half),
// nh = w>>1 (n-half). V+Q chunks (32 n) staged to LDS once per block
// (double-buffered; global loads land in regs before the barrier so their
// latency hides); both mh waves consume the same staged chunk -> 4x less
// L2 traffic than the m-tile-16 version (the measured bottleneck).
// Per chunk/wave: 4 score MFMAs (K=8-padded) + exp + pack -> per-wave dbuf
// Pb + 8 PV MFMAs (P consumed one iter after write: round-trip off the
// critical path). No max-subtraction (logits <= ~3, fp32 exp safe).
// ---------------------------------------------------------------------------
__global__ __launch_bounds__(256) void attn_kernel(
    const unsigned short* __restrict__ Qt,
    const unsigned short* __restrict__ Kt,
    const unsigned short* __restrict__ Vsw,
    const float* __restrict__ x, const float* __restrict__ gamma,
    float* __restrict__ out)
{
    __shared__ __align__(16) unsigned short Vs[2][2][2048];   // [dbuf][nh][ct*512+lane*8+j]
    __shared__ __align__(16) unsigned short Qs[2][2][256];    // [dbuf][nh][n_local*8+j]
    __shared__ __align__(16) unsigned short Pb[4][2][32][40]; // [wave][dbuf][m][n]
    __shared__ float Ored[2][2][64][33];                      // [nh][mh][c][m_local32]
    __shared__ float Lred[4][2][16];                          // [wave][msub][l15]
    __shared__ float Lf[64];

    const int t    = threadIdx.x;
    const int w    = t >> 6;
    const int lane = t & 63;
    const int quad = lane >> 4;
    const int l15  = lane & 15;
    const int mh   = w & 1;
    const int nh   = w >> 1;
    const int b    = blockIdx.y;
    const int m0   = blockIdx.x * 64;

    const short8v zfrag = {0, 0, 0, 0, 0, 0, 0, 0};
    const float4v zacc  = {0.f, 0.f, 0.f, 0.f};

    // K-side B fragments for this wave's two 16-m columns (quad0 = real K)
    short8v bk0 = zfrag, bk1 = zfrag;
    if (quad == 0) {
        bk0 = *(const short8v*)(Kt + (size_t)(b * NN + m0 + mh * 32 + l15) * 8);
        bk1 = *(const short8v*)(Kt + (size_t)(b * NN + m0 + mh * 32 + 16 + l15) * 8);
    }

    float4v acc[4][2];
    #pragma unroll
    for (int ct = 0; ct < 4; ++ct) { acc[ct][0] = zacc; acc[ct][1] = zacc; }
    float Lacc0 = 0.f, Lacc1 = 0.f;

    // staging roles (all 256 threads)
    const int sct = t >> 6, ss = t & 63;
    const unsigned short* vsrc0 = Vsw + ((size_t)(b * 4 + sct) * 128 + 0)  * 512 + ss * 8;
    const unsigned short* vsrc1 = Vsw + ((size_t)(b * 4 + sct) * 128 + 64) * 512 + ss * 8;
    const int qnh = t >> 5, qrw = t & 31;     // threads 0..63 stage Q
    const unsigned short* qsrc = Qt + ((size_t)b * NN + qnh * 64 * 32 + qrw) * 8;

    // ---- prologue: stage chunk 0 into buf 0
    {
        *(short8v*)&Vs[0][0][sct * 512 + ss * 8] = *(const short8v*)(vsrc0);
        *(short8v*)&Vs[0][1][sct * 512 + ss * 8] = *(const short8v*)(vsrc1);
        if (t < 64)
            *(short8v*)&Qs[0][qnh][qrw * 8] = *(const short8v*)(qsrc);
    }

    for (int i = 0; i <= 64; ++i) {
        // 1. issue chunk-(i+1) global loads into regs (latency hides below)
        short8v vreg0, vreg1, qreg;
        if (i <= 62) {
            vreg0 = *(const short8v*)(vsrc0 + (size_t)(i + 1) * 512);
            vreg1 = *(const short8v*)(vsrc1 + (size_t)(i + 1) * 512);
            if (t < 64) qreg = *(const short8v*)(qsrc + (size_t)(i + 1) * 32 * 8);
        }

        // 2. consume-phase LDS reads for chunk i-1 (before barrier!)
        short8v av0, av1, av2, av3, bp0, bp1;
        if (i >= 1) {
            const int rb = (i - 1) & 1;
            av0 = *(const short8v*)&Vs[rb][nh][0 * 512 + lane * 8];
            av1 = *(const short8v*)&Vs[rb][nh][1 * 512 + lane * 8];
            av2 = *(const short8v*)&Vs[rb][nh][2 * 512 + lane * 8];
            av3 = *(const short8v*)&Vs[rb][nh][3 * 512 + lane * 8];
            bp0 = *(const short8v*)&Pb[w][rb][l15][quad * 8];
            bp1 = *(const short8v*)&Pb[w][rb][16 + l15][quad * 8];
        }
        __syncthreads();

        if (i <= 63) {
            // 3. store staged regs -> buf (i+1)&1
            if (i <= 62) {
                const int wb = (i + 1) & 1;
                *(short8v*)&Vs[wb][0][sct * 512 + ss * 8] = vreg0;
                *(short8v*)&Vs[wb][1][sct * 512 + ss * 8] = vreg1;
                if (t < 64) *(short8v*)&Qs[wb][qnh][qrw * 8] = qreg;
            }

            // 4. scores for chunk i
            const int cb = i & 1;
            short8v aq0 = zfrag, aq1 = zfrag;
            if (quad == 0) {
                aq0 = *(const short8v*)&Qs[cb][nh][l15 * 8];
                aq1 = *(const short8v*)&Qs[cb][nh][(16 + l15) * 8];
            }
            float4v s00 = __builtin_amdgcn_mfma_f32_16x16x32_bf16(aq0, bk0, zacc, 0, 0, 0);
            float4v s01 = __builtin_amdgcn_mfma_f32_16x16x32_bf16(aq0, bk1, zacc, 0, 0, 0);
            float4v s10 = __builtin_amdgcn_mfma_f32_16x16x32_bf16(aq1, bk0, zacc, 0, 0, 0);
            float4v s11 = __builtin_amdgcn_mfma_f32_16x16x32_bf16(aq1, bk1, zacc, 0, 0, 0);

            float p00[4], p01[4], p10[4], p11[4];
            #pragma unroll
            for (int j = 0; j < 4; ++j) {
                p00[j] = __expf(s00[j]); p01[j] = __expf(s01[j]);
                p10[j] = __expf(s10[j]); p11[j] = __expf(s11[j]);
            }
            #pragma unroll
            for (int j = 0; j < 4; ++j) {
                Lacc0 += p00[j] + p10[j];
                Lacc1 += p01[j] + p11[j];
            }
            short4v k00, k01, k10, k11;
            #pragma unroll
            for (int j = 0; j < 4; ++j) {
                k00[j] = (short)f2bf_rn(p00[j]); k01[j] = (short)f2bf_rn(p01[j]);
                k10[j] = (short)f2bf_rn(p10[j]); k11[j] = (short)f2bf_rn(p11[j]);
            }
            // Pb[m][n]: row m = msub*16+l15, cols n = nsub*16+quad*4 ..+3
            *(short4v*)&Pb[w][cb][l15][quad * 4]           = k00;
            *(short4v*)&Pb[w][cb][l15][16 + quad * 4]      = k10;
            *(short4v*)&Pb[w][cb][16 + l15][quad * 4]      = k01;
            *(short4v*)&Pb[w][cb][16 + l15][16 + quad * 4] = k11;
        }

        // 5. PV for chunk i-1
        if (i >= 1) {
            acc[0][0] = __builtin_amdgcn_mfma_f32_16x16x32_bf16(av0, bp0, acc[0][0], 0, 0, 0);
            acc[1][0] = __builtin_amdgcn_mfma_f32_16x16x32_bf16(av1, bp0, acc[1][0], 0, 0, 0);
            acc[2][0] = __builtin_amdgcn_mfma_f32_16x16x32_bf16(av2, bp0, acc[2][0], 0, 0, 0);
            acc[3][0] = __builtin_amdgcn_mfma_f32_16x16x32_bf16(av3, bp0, acc[3][0], 0, 0, 0);
            acc[0][1] = __builtin_amdgcn_mfma_f32_16x16x32_bf16(av0, bp1, acc[0][1], 0, 0, 0);
            acc[1][1] = __builtin_amdgcn_mfma_f32_16x16x32_bf16(av1, bp1, acc[1][1], 0, 0, 0);
            acc[2][1] = __builtin_amdgcn_mfma_f32_16x16x32_bf16(av2, bp1, acc[2][1], 0, 0, 0);
            acc[3][1] = __builtin_amdgcn_mfma_f32_16x16x32_bf16(av3, bp1, acc[3][1], 0, 0, 0);
        }
    }

    // ---- L: combine quads within wave, store per-wave column sums
    Lacc0 += __shfl_xor(Lacc0, 16, 64);
    Lacc0 += __shfl_xor(Lacc0, 32, 64);
    Lacc1 += __shfl_xor(Lacc1, 16, 64);
    Lacc1 += __shfl_xor(Lacc1, 32, 64);
    if (lane < 16) {
        Lred[w][0][lane] = Lacc0;
        Lred[w][1][lane] = Lacc1;
    }

    // ---- dump per-wave partial O
    #pragma unroll
    for (int ct = 0; ct < 4; ++ct)
        #pragma unroll
        for (int msub = 0; msub < 2; ++msub)
            #pragma unroll
            for (int r = 0; r < 4; ++r)
                Ored[nh][mh][ct * 16 + quad * 4 + r][msub * 16 + l15] = acc[ct][msub][r];
    __syncthreads();

    if (t < 64) {
        int mh_t = t >> 5, msub_t = (t >> 4) & 1, l_t = t & 15;
        Lf[t] = 1.f / (Lred[mh_t][msub_t][l_t] + Lred[2 + mh_t][msub_t][l_t]);
    }
    __syncthreads();

    // ---- fused epilogue: gamma * O / L + x, 16 floats per thread
    {
        const float gv = gamma[0];
        int c = t >> 2, q = t & 3;
        #pragma unroll
        for (int i4 = 0; i4 < 4; ++i4) {
            int ml64 = q * 16 + i4 * 4;
            int mhh = ml64 >> 5, ml32 = ml64 & 31;
            size_t gbase = (size_t)(b * 64 + c) * NN + m0 + ml64;
            float4 xv = *(const float4*)&x[gbase];
            float4 r;
            #pragma unroll
            for (int e = 0; e < 4; ++e) {
                float o = Ored[0][mhh][c][ml32 + e] + Ored[1][mhh][c][ml32 + e];
                ((float*)&r)[e] = gv * o * Lf[ml64 + e] + ((float*)&xv)[e];
            }
            *(float4*)&out[gbase] = r;
        }
    }
}

extern "C" void kernel_launch(void* const* d_in, const int* in_sizes, int n_in,
                              void* d_out, int out_size, void* d_ws, size_t ws_size,
                              hipStream_t stream) {
    const float* x     = (const float*)d_in[0];
    const float* Wq    = (const float*)d_in[1];
    const float* Wk    = (const float*)d_in[2];
    const float* Wv    = (const float*)d_in[3];
    const float* gamma = (const float*)d_in[4];
    float* out = (float*)d_out;

    unsigned short* ws = (unsigned short*)d_ws;
    unsigned short* Qt  = ws;                        // [B][N][8]  bf16, 256 KB
    unsigned short* Kt  = Qt + (size_t)BB * NN * 8;  // [B][N][8]  bf16, 256 KB
    unsigned short* Vsw = Kt + (size_t)BB * NN * 8;  // [B][4][128][512] bf16, 2 MB

    qkv_kernel<<<dim3(NN / 32, BB), 256, 0, stream>>>(x, Wq, Wk, Wv, Qt, Kt, Vsw);
    attn_kernel<<<dim3(NN / 64, BB), 256, 0, stream>>>(Qt, Kt, Vsw, x, gamma, out);
}

// Round 8
// 97.400 us; speedup vs baseline: 1.1868x; 1.1868x over previous
//
#include <hip/hip_runtime.h>

#define BB 4
#define NN 4096

typedef __attribute__((ext_vector_type(8))) short short8v;   // 8 bf16 = 4 VGPRs
typedef __attribute__((ext_vector_type(4))) short short4v;   // 4 bf16 = 2 VGPRs
typedef __attribute__((ext_vector_type(4))) float float4v;   // MFMA acc

__device__ __forceinline__ unsigned short f2bf_rn(float f) {
    unsigned u = __float_as_uint(f);
    u += 0x7FFFu + ((u >> 16) & 1u);          // round-to-nearest-even
    return (unsigned short)(u >> 16);
}

// ---------------------------------------------------------------------------
// Kernel 1: fused QKV projection, scalar-broadcast GEMM, n-tile 32 (r7 ver.).
// Outputs: Qt[b][n][8], Kt[b][n][8] (16 B rows); Vsw 1 KB chunks per
// (b,ct,nb): elem[lane*8+j] = V[ct*16+(lane&15)][nb*32+(lane>>4)*8+j].
// ---------------------------------------------------------------------------
__global__ __launch_bounds__(256) void qkv_kernel(
    const float* __restrict__ x,
    const float* __restrict__ Wq, const float* __restrict__ Wk,
    const float* __restrict__ Wv,
    unsigned short* __restrict__ Qt, unsigned short* __restrict__ Kt,
    unsigned short* __restrict__ Vsw)
{
    __shared__ float xs[64][36];            // [c][n] fp32
    __shared__ float wl[64][81];            // [c][o] transposed weights
    __shared__ unsigned short Ot[80][40];   // [o][n] bf16 staging

    const int t  = threadIdx.x;
    const int b  = blockIdx.y;
    const int nb = blockIdx.x;               // 32-n tile == one Vsw chunk index
    const int n0 = nb * 32;

    #pragma unroll
    for (int i = 0; i < 20; ++i) {
        int idx = t + 256 * i;               // 5120 = 80*64
        int r = idx >> 6, c = idx & 63;
        float w;
        if (r < 8)       w = Wq[r * 64 + c];
        else if (r < 16) w = Wk[(r - 8) * 64 + c];
        else             w = Wv[(r - 16) * 64 + c];
        wl[c][r] = w;
    }
    #pragma unroll
    for (int i = 0; i < 2; ++i) {
        int idx = t + 256 * i;               // 512 float4 slots
        int c = idx >> 3, n4 = (idx & 7) * 4;
        *(float4*)&xs[c][n4] = *(const float4*)&x[(size_t)(b * 64 + c) * NN + n0 + n4];
    }
    __syncthreads();

    const int n2 = (t & 15) * 2;
    const int og = t >> 4;

    float acc[5][2];
    #pragma unroll
    for (int k = 0; k < 5; ++k) { acc[k][0] = 0.f; acc[k][1] = 0.f; }

    for (int c = 0; c < 64; ++c) {
        float2 xv = *(const float2*)&xs[c][n2];
        #pragma unroll
        for (int k = 0; k < 5; ++k) {
            float wv = wl[c][og * 5 + k];
            acc[k][0] += wv * xv.x;
            acc[k][1] += wv * xv.y;
        }
    }

    #pragma unroll
    for (int k = 0; k < 5; ++k) {
        Ot[og * 5 + k][n2]     = f2bf_rn(acc[k][0]);
        Ot[og * 5 + k][n2 + 1] = f2bf_rn(acc[k][1]);
    }
    __syncthreads();

    if (t < 64) {
        int n = t & 31;
        int rbase = (t < 32) ? 0 : 8;
        short8v p;
        #pragma unroll
        for (int j = 0; j < 8; ++j) p[j] = (short)Ot[rbase + j][n];
        unsigned short* dst = ((t < 32) ? Qt : Kt) + ((size_t)b * NN + n0 + n) * 8;
        *(short8v*)dst = p;
    }

    {
        int ct = t >> 6, l = t & 63;
        unsigned short* cb = Vsw + ((size_t)(b * 4 + ct) * 128 + nb) * 512;
        short8v d = *(short8v*)&Ot[16 + ct * 16 + (l & 15)][(l >> 4) * 8];
        *(short8v*)(cb + l * 8) = d;
    }
}

// ---------------------------------------------------------------------------
// Kernel 2: MFMA streaming attention, independent waves (r5/r6 structure,
// proven latency-tolerant: NO in-loop barriers), m-tile 32 per wave.
// Grid (128, 4) = 512 blocks (2/CU, 8 waves/CU). Wave w owns n in
// [w*1024,(w+1)*1024), 32 chunks of 32 n. Per chunk: 4 score MFMAs
// (K=8-padded), 16 exp, pack -> per-wave dbuf Pb (consumed next iter:
// ds_write->ds_read off the critical path), 8 PV MFMAs on swizzled
// (coalesced) V. Doubling m per wave halves total V+Q L2 traffic vs r6.
// No max-subtraction (logits <= ~3, fp32 exp safe).
// ---------------------------------------------------------------------------
__global__ __launch_bounds__(256, 2) void attn_kernel(
    const unsigned short* __restrict__ Qt,
    const unsigned short* __restrict__ Kt,
    const unsigned short* __restrict__ Vsw,
    const float* __restrict__ x, const float* __restrict__ gamma,
    float* __restrict__ out)
{
    __shared__ __align__(16) unsigned short Pb[4][2][32][40]; // [wave][dbuf][m][n]
    __shared__ float Ored[4][64][33];                         // [wave][c][m_local]
    __shared__ float Lred[4][2][16];                          // [wave][msub][l15]
    __shared__ float Lf[32];

    const int t    = threadIdx.x;
    const int w    = t >> 6;
    const int lane = t & 63;
    const int quad = lane >> 4;
    const int l15  = lane & 15;
    const int b    = blockIdx.y;
    const int m0   = blockIdx.x * 32;

    const short8v zfrag = {0, 0, 0, 0, 0, 0, 0, 0};
    const float4v zacc  = {0.f, 0.f, 0.f, 0.f};

    // K-side B fragments for the two 16-m columns (quad0 = real K, K=8 pad)
    short8v bk0 = zfrag, bk1 = zfrag;
    if (quad == 0) {
        bk0 = *(const short8v*)(Kt + (size_t)(b * NN + m0 + l15) * 8);
        bk1 = *(const short8v*)(Kt + (size_t)(b * NN + m0 + 16 + l15) * 8);
    }

    float4v acc[4][2];
    #pragma unroll
    for (int ct = 0; ct < 4; ++ct) { acc[ct][0] = zacc; acc[ct][1] = zacc; }
    float Lacc0 = 0.f, Lacc1 = 0.f;

    const unsigned short* qrow = Qt + (size_t)(b * NN + w * 1024 + l15) * 8;
    const unsigned short* vptr = Vsw + ((size_t)b * 4 * 128 + w * 32) * 512 + lane * 8;

    // ---- prolog: chunk 0 scores -> Pb[w][0]; V chunk 0 into regs
    short8v av0 = *(const short8v*)(vptr);
    short8v av1 = *(const short8v*)(vptr + 1 * 128 * 512);
    short8v av2 = *(const short8v*)(vptr + 2 * 128 * 512);
    short8v av3 = *(const short8v*)(vptr + 3 * 128 * 512);
    {
        short8v aq0 = zfrag, aq1 = zfrag;
        if (quad == 0) {
            aq0 = *(const short8v*)(qrow);
            aq1 = *(const short8v*)(qrow + 16 * 8);
        }
        float4v s00 = __builtin_amdgcn_mfma_f32_16x16x32_bf16(aq0, bk0, zacc, 0, 0, 0);
        float4v s01 = __builtin_amdgcn_mfma_f32_16x16x32_bf16(aq0, bk1, zacc, 0, 0, 0);
        float4v s10 = __builtin_amdgcn_mfma_f32_16x16x32_bf16(aq1, bk0, zacc, 0, 0, 0);
        float4v s11 = __builtin_amdgcn_mfma_f32_16x16x32_bf16(aq1, bk1, zacc, 0, 0, 0);
        float p00[4], p01[4], p10[4], p11[4];
        #pragma unroll
        for (int j = 0; j < 4; ++j) {
            p00[j] = __expf(s00[j]); p01[j] = __expf(s01[j]);
            p10[j] = __expf(s10[j]); p11[j] = __expf(s11[j]);
        }
        #pragma unroll
        for (int j = 0; j < 4; ++j) {
            Lacc0 += p00[j] + p10[j];
            Lacc1 += p01[j] + p11[j];
        }
        short4v k00, k01, k10, k11;
        #pragma unroll
        for (int j = 0; j < 4; ++j) {
            k00[j] = (short)f2bf_rn(p00[j]); k01[j] = (short)f2bf_rn(p01[j]);
            k10[j] = (short)f2bf_rn(p10[j]); k11[j] = (short)f2bf_rn(p11[j]);
        }
        *(short4v*)&Pb[w][0][l15][quad * 4]           = k00;
        *(short4v*)&Pb[w][0][l15][16 + quad * 4]      = k10;
        *(short4v*)&Pb[w][0][16 + l15][quad * 4]      = k01;
        *(short4v*)&Pb[w][0][16 + l15][16 + quad * 4] = k11;
    }

    for (int it = 0; it < 31; ++it) {
        const int itn = it + 1;

        // ---- V fragments for chunk itn (consumed next iter)
        short8v avn0 = *(const short8v*)(vptr + itn * 512);
        short8v avn1 = *(const short8v*)(vptr + 1 * 128 * 512 + itn * 512);
        short8v avn2 = *(const short8v*)(vptr + 2 * 128 * 512 + itn * 512);
        short8v avn3 = *(const short8v*)(vptr + 3 * 128 * 512 + itn * 512);

        // ---- scores for chunk itn -> Pb[w][itn&1]
        short8v aq0 = zfrag, aq1 = zfrag;
        if (quad == 0) {
            aq0 = *(const short8v*)(qrow + (size_t)(itn * 32) * 8);
            aq1 = *(const short8v*)(qrow + (size_t)(itn * 32 + 16) * 8);
        }
        float4v s00 = __builtin_amdgcn_mfma_f32_16x16x32_bf16(aq0, bk0, zacc, 0, 0, 0);
        float4v s01 = __builtin_amdgcn_mfma_f32_16x16x32_bf16(aq0, bk1, zacc, 0, 0, 0);
        float4v s10 = __builtin_amdgcn_mfma_f32_16x16x32_bf16(aq1, bk0, zacc, 0, 0, 0);
        float4v s11 = __builtin_amdgcn_mfma_f32_16x16x32_bf16(aq1, bk1, zacc, 0, 0, 0);
        float p00[4], p01[4], p10[4], p11[4];
        #pragma unroll
        for (int j = 0; j < 4; ++j) {
            p00[j] = __expf(s00[j]); p01[j] = __expf(s01[j]);
            p10[j] = __expf(s10[j]); p11[j] = __expf(s11[j]);
        }
        #pragma unroll
        for (int j = 0; j < 4; ++j) {
            Lacc0 += p00[j] + p10[j];
            Lacc1 += p01[j] + p11[j];
        }
        short4v k00, k01, k10, k11;
        #pragma unroll
        for (int j = 0; j < 4; ++j) {
            k00[j] = (short)f2bf_rn(p00[j]); k01[j] = (short)f2bf_rn(p01[j]);
            k10[j] = (short)f2bf_rn(p10[j]); k11[j] = (short)f2bf_rn(p11[j]);
        }
        *(short4v*)&Pb[w][itn & 1][l15][quad * 4]           = k00;
        *(short4v*)&Pb[w][itn & 1][l15][16 + quad * 4]      = k10;
        *(short4v*)&Pb[w][itn & 1][16 + l15][quad * 4]      = k01;
        *(short4v*)&Pb[w][itn & 1][16 + l15][16 + quad * 4] = k11;

        // ---- PV for chunk it (P written a full iteration ago)
        short8v bp0 = *(const short8v*)&Pb[w][it & 1][l15][quad * 8];
        short8v bp1 = *(const short8v*)&Pb[w][it & 1][16 + l15][quad * 8];
        acc[0][0] = __builtin_amdgcn_mfma_f32_16x16x32_bf16(av0, bp0, acc[0][0], 0, 0, 0);
        acc[1][0] = __builtin_amdgcn_mfma_f32_16x16x32_bf16(av1, bp0, acc[1][0], 0, 0, 0);
        acc[2][0] = __builtin_amdgcn_mfma_f32_16x16x32_bf16(av2, bp0, acc[2][0], 0, 0, 0);
        acc[3][0] = __builtin_amdgcn_mfma_f32_16x16x32_bf16(av3, bp0, acc[3][0], 0, 0, 0);
        acc[0][1] = __builtin_amdgcn_mfma_f32_16x16x32_bf16(av0, bp1, acc[0][1], 0, 0, 0);
        acc[1][1] = __builtin_amdgcn_mfma_f32_16x16x32_bf16(av1, bp1, acc[1][1], 0, 0, 0);
        acc[2][1] = __builtin_amdgcn_mfma_f32_16x16x32_bf16(av2, bp1, acc[2][1], 0, 0, 0);
        acc[3][1] = __builtin_amdgcn_mfma_f32_16x16x32_bf16(av3, bp1, acc[3][1], 0, 0, 0);

        av0 = avn0; av1 = avn1; av2 = avn2; av3 = avn3;
    }

    // ---- epilog: PV for chunk 31 (31&1 = 1)
    {
        short8v bp0 = *(const short8v*)&Pb[w][1][l15][quad * 8];
        short8v bp1 = *(const short8v*)&Pb[w][1][16 + l15][quad * 8];
        acc[0][0] = __builtin_amdgcn_mfma_f32_16x16x32_bf16(av0, bp0, acc[0][0], 0, 0, 0);
        acc[1][0] = __builtin_amdgcn_mfma_f32_16x16x32_bf16(av1, bp0, acc[1][0], 0, 0, 0);
        acc[2][0] = __builtin_amdgcn_mfma_f32_16x16x32_bf16(av2, bp0, acc[2][0], 0, 0, 0);
        acc[3][0] = __builtin_amdgcn_mfma_f32_16x16x32_bf16(av3, bp0, acc[3][0], 0, 0, 0);
        acc[0][1] = __builtin_amdgcn_mfma_f32_16x16x32_bf16(av0, bp1, acc[0][1], 0, 0, 0);
        acc[1][1] = __builtin_amdgcn_mfma_f32_16x16x32_bf16(av1, bp1, acc[1][1], 0, 0, 0);
        acc[2][1] = __builtin_amdgcn_mfma_f32_16x16x32_bf16(av2, bp1, acc[2][1], 0, 0, 0);
        acc[3][1] = __builtin_amdgcn_mfma_f32_16x16x32_bf16(av3, bp1, acc[3][1], 0, 0, 0);
    }

    // ---- combine quads' L partials within the wave
    Lacc0 += __shfl_xor(Lacc0, 16, 64);
    Lacc0 += __shfl_xor(Lacc0, 32, 64);
    Lacc1 += __shfl_xor(Lacc1, 16, 64);
    Lacc1 += __shfl_xor(Lacc1, 32, 64);
    if (lane < 16) {
        Lred[w][0][lane] = Lacc0;
        Lred[w][1][lane] = Lacc1;
    }

    // ---- dump per-wave partial O: row c = ct*16+quad*4+r, col msub*16+l15
    #pragma unroll
    for (int ct = 0; ct < 4; ++ct)
        #pragma unroll
        for (int msub = 0; msub < 2; ++msub)
            #pragma unroll
            for (int r = 0; r < 4; ++r)
                Ored[w][ct * 16 + quad * 4 + r][msub * 16 + l15] = acc[ct][msub][r];
    __syncthreads();

    if (t < 32) {
        int msub = t >> 4, l = t & 15;
        Lf[t] = 1.f / (Lred[0][msub][l] + Lred[1][msub][l]
                     + Lred[2][msub][l] + Lred[3][msub][l]);
    }
    __syncthreads();

    // ---- vectorized epilogue: thread -> (c = t>>2, 8 consecutive m)
    {
        const float gv = gamma[0];
        int c = t >> 2, ml = (t & 3) * 8;
        size_t gbase = (size_t)(b * 64 + c) * NN + m0 + ml;
        #pragma unroll
        for (int h = 0; h < 2; ++h) {
            float4 xv = *(const float4*)&x[gbase + h * 4];
            float4 r;
            #pragma unroll
            for (int e = 0; e < 4; ++e) {
                int mm = ml + h * 4 + e;
                float o = Ored[0][c][mm] + Ored[1][c][mm]
                        + Ored[2][c][mm] + Ored[3][c][mm];
                ((float*)&r)[e] = gv * o * Lf[mm] + ((float*)&xv)[e];
            }
            *(float4*)&out[gbase + h * 4] = r;
        }
    }
}

extern "C" void kernel_launch(void* const* d_in, const int* in_sizes, int n_in,
                              void* d_out, int out_size, void* d_ws, size_t ws_size,
                              hipStream_t stream) {
    const float* x     = (const float*)d_in[0];
    const float* Wq    = (const float*)d_in[1];
    const float* Wk    = (const float*)d_in[2];
    const float* Wv    = (const float*)d_in[3];
    const float* gamma = (const float*)d_in[4];
    float* out = (float*)d_out;

    unsigned short* ws = (unsigned short*)d_ws;
    unsigned short* Qt  = ws;                        // [B][N][8]  bf16, 256 KB
    unsigned short* Kt  = Qt + (size_t)BB * NN * 8;  // [B][N][8]  bf16, 256 KB
    unsigned short* Vsw = Kt + (size_t)BB * NN * 8;  // [B][4][128][512] bf16, 2 MB

    qkv_kernel<<<dim3(NN / 32, BB), 256, 0, stream>>>(x, Wq, Wk, Wv, Qt, Kt, Vsw);
    attn_kernel<<<dim3(NN / 32, BB), 256, 0, stream>>>(Qt, Kt, Vsw, x, gamma, out);
}